// Round 1
// baseline (374.292 us; speedup 1.0000x reference)
//
#include <hip/hip_runtime.h>
#include <cmath>
#include <cstdint>
#include <cstddef>

#define NT 8192   // tokens
#define MD 4096   // model dim
#define NE 64     // experts

// Output layout (all float32):
// [0]                  l_loss
// [1, 1+2NT)           gates_k [2][NT]
// [1+2NT, 1+4NT)       idx     [2][NT] (ints as float)
// [1+4NT, 1+6NT)       locations [2][NT] (ints as float)
static constexpr int OFF_GATES = 1;
static constexpr int OFF_IDX   = 1 + 2 * NT;
static constexpr int OFF_LOC   = 1 + 4 * NT;

// K1: partial GEMM. grid (32 token-blocks, nd d-chunks), block 512.
// Thread = (token, expert-half). 32 fp32 accumulators; wg goes through the
// scalar path (uniform address), x via per-lane dwordx4 (L1 line reuse).
__global__ __launch_bounds__(512, 2)
void k1_gemm(const float* __restrict__ x, const float* __restrict__ wg,
             float* __restrict__ part, int dch) {
  const int tid   = threadIdx.x;
  const int token = blockIdx.x * 256 + (tid & 255);
  const int ehalf = __builtin_amdgcn_readfirstlane(tid >> 8);  // wave-uniform
  const int d0    = blockIdx.y * dch;

  float acc[32];
#pragma unroll
  for (int i = 0; i < 32; ++i) acc[i] = 0.f;

  const float* xp = x + (size_t)token * MD + d0;
  const float* wp = wg + (size_t)(ehalf * 32) * MD + d0;

  for (int d = 0; d < dch; d += 8) {
    float4 xa = *(const float4*)(xp + d);
    float4 xb = *(const float4*)(xp + d + 4);
#pragma unroll
    for (int e = 0; e < 32; ++e) {
      const float* w = wp + (size_t)e * MD + d;
      acc[e] = fmaf(xa.x, w[0], acc[e]);
      acc[e] = fmaf(xa.y, w[1], acc[e]);
      acc[e] = fmaf(xa.z, w[2], acc[e]);
      acc[e] = fmaf(xa.w, w[3], acc[e]);
      acc[e] = fmaf(xb.x, w[4], acc[e]);
      acc[e] = fmaf(xb.y, w[5], acc[e]);
      acc[e] = fmaf(xb.z, w[6], acc[e]);
      acc[e] = fmaf(xb.w, w[7], acc[e]);
    }
  }

  // part[nd][token][64]
  float* pp = part + ((size_t)blockIdx.y * NT + token) * NE + ehalf * 32;
#pragma unroll
  for (int i = 0; i < 32; i += 4)
    *(float4*)(pp + i) = make_float4(acc[i], acc[i + 1], acc[i + 2], acc[i + 3]);
}

// K2: reduce partials -> logits[64]/token, top-2, softmax, gates, idx,
// per-block column sums of gates (me partials). grid 128, block 64 (1 wave).
__global__ void k2_topk(const float* __restrict__ part, float* __restrict__ out,
                        float* __restrict__ me_partial, int nd) {
  const int lane  = threadIdx.x;            // 0..63
  const int token = blockIdx.x * 64 + lane;

  float l[NE];
#pragma unroll
  for (int e = 0; e < NE; ++e) l[e] = 0.f;
  for (int c = 0; c < nd; ++c) {
    const float4* p4 = (const float4*)(part + ((size_t)c * NT + token) * NE);
#pragma unroll
    for (int q = 0; q < 16; ++q) {
      float4 v = p4[q];
      l[4 * q + 0] += v.x; l[4 * q + 1] += v.y;
      l[4 * q + 2] += v.z; l[4 * q + 3] += v.w;
    }
  }

  // top-2 with jax tie-breaking (lowest index first): strict > ascending scan
  float m1 = -INFINITY; int i1 = 0;
#pragma unroll
  for (int e = 0; e < NE; ++e) if (l[e] > m1) { m1 = l[e]; i1 = e; }
  float m2 = -INFINITY; int i2 = 0;
#pragma unroll
  for (int e = 0; e < NE; ++e) if (e != i1 && l[e] > m2) { m2 = l[e]; i2 = e; }

  // full softmax (needed for me column sums)
  float s = 0.f;
#pragma unroll
  for (int e = 0; e < NE; ++e) { l[e] = __expf(l[e] - m1); s += l[e]; }
  const float inv_s = 1.f / s;

  // normalized top-2 gates: softmax denom cancels
  const float g2 = __expf(m2 - m1);
  const float dn = 1.f + g2;
  out[OFF_GATES + token]      = 1.f / dn;
  out[OFF_GATES + NT + token] = g2 / dn;
  out[OFF_IDX + token]        = (float)i1;
  out[OFF_IDX + NT + token]   = (float)i2;

  // transpose-reduce gates over the wave's 64 tokens via LDS (pad 65: conflict-free)
  __shared__ float lds[64 * 65];
#pragma unroll
  for (int e = 0; e < NE; ++e) lds[lane * 65 + e] = l[e] * inv_s;
  __syncthreads();
  float col = 0.f;
#pragma unroll
  for (int t = 0; t < 64; ++t) col += lds[t * 65 + lane];
  me_partial[blockIdx.x * 64 + lane] = col;
}

// K3: locations via wave-per-expert ballot scan (exact, deterministic),
// plus per-expert l_loss partial. grid 64 (1 wave per expert).
__global__ void k3_loc(float* out, const float* __restrict__ me_partial,
                       float* __restrict__ lloss_part) {
  const int e    = blockIdx.x;
  const int lane = threadIdx.x;

  int base = 0;  // k = 0 stream
  for (int c = 0; c < NT / 64; ++c) {
    int ii = (int)out[OFF_IDX + c * 64 + lane];
    unsigned long long m = __ballot(ii == e);
    if (ii == e)
      out[OFF_LOC + c * 64 + lane] =
          (float)(base + __popcll(m & ((1ULL << lane) - 1ULL)));
    base += __popcll(m);
  }
  const int count0 = base;  // == ce[e] == acc[1][e]

  for (int c = 0; c < NT / 64; ++c) {  // k = 1 stream, offset by count0
    int ii = (int)out[OFF_IDX + NT + c * 64 + lane];
    unsigned long long m = __ballot(ii == e);
    if (ii == e)
      out[OFF_LOC + NT + c * 64 + lane] =
          (float)(base + __popcll(m & ((1ULL << lane) - 1ULL)));
    base += __popcll(m);
  }

  // me[e] = sum of 128 per-block partials; lane b handles blocks b, b+64
  float me = me_partial[lane * NE + e] + me_partial[(lane + 64) * NE + e];
#pragma unroll
  for (int off = 1; off < 64; off <<= 1) me += __shfl_xor(me, off, 64);
  if (lane == 0) lloss_part[e] = me * (float)count0;
}

// K4: final l_loss reduce. 1 wave.
__global__ void k4_loss(const float* __restrict__ lloss_part, float* __restrict__ out) {
  const int lane = threadIdx.x;
  float v = lloss_part[lane];
#pragma unroll
  for (int off = 1; off < 64; off <<= 1) v += __shfl_xor(v, off, 64);
  if (lane == 0) out[0] = v * ((float)NE / ((float)NT * (float)NT));
}

extern "C" void kernel_launch(void* const* d_in, const int* in_sizes, int n_in,
                              void* d_out, int out_size, void* d_ws, size_t ws_size,
                              hipStream_t stream) {
  const float* x  = (const float*)d_in[0];
  const float* wg = (const float*)d_in[1];
  float* out = (float*)d_out;

  // choose D-split so partials fit the workspace
  int nd = 8;
  while (nd > 1 &&
         ((size_t)nd * NT * NE + 128 * NE + NE) * sizeof(float) > ws_size)
    nd >>= 1;
  const int dch = MD / nd;

  float* part       = (float*)d_ws;
  float* me_partial = part + (size_t)nd * NT * NE;
  float* lloss_part = me_partial + 128 * NE;

  hipLaunchKernelGGL(k1_gemm, dim3(32, nd), dim3(512), 0, stream, x, wg, part, dch);
  hipLaunchKernelGGL(k2_topk, dim3(NT / 64), dim3(64), 0, stream, part, out, me_partial, nd);
  hipLaunchKernelGGL(k3_loc,  dim3(NE), dim3(64), 0, stream, out, me_partial, lloss_part);
  hipLaunchKernelGGL(k4_loss, dim3(1), dim3(64), 0, stream, lloss_part, out);
}

// Round 2
// 291.898 us; speedup vs baseline: 1.2823x; 1.2823x over previous
//
#include <hip/hip_runtime.h>
#include <cmath>
#include <cstdint>
#include <cstddef>

#define NT 8192   // tokens
#define MD 4096   // model dim
#define NE 64     // experts
#define NCHUNK 128  // NT/64

// Output layout (all float32):
// [0] l_loss | [1,1+2NT) gates_k[2][NT] | idx[2][NT] | locations[2][NT]
static constexpr int OFF_GATES = 1;
static constexpr int OFF_IDX   = 1 + 2 * NT;
static constexpr int OFF_LOC   = 1 + 4 * NT;

__device__ __forceinline__ void gload_lds16(const float* g, float* l) {
  __builtin_amdgcn_global_load_lds(
      (const __attribute__((address_space(1))) void*)g,
      (__attribute__((address_space(3))) void*)l, 16, 0, 0);
}

// K1: skinny GEMM logits += x[256 tok tile] . wg[32 expert half]^T over a k-chunk.
// grid (64, ks), block 512 (8 waves). Wave = 256 tokens x 4 experts.
// Thread: 4 tokens x 4 experts, 16 fp32 acc. wg via LDS broadcast, x per-lane rows.
__global__ __launch_bounds__(512, 4)
void k1_gemm(const float* __restrict__ x, const float* __restrict__ wg,
             float* __restrict__ part, int kchunk) {
  __shared__ float wlds[2][32 * 64];   // [expert-in-half][k] per buffer, 8KB each
  const int tid  = threadIdx.x;
  const int lane = tid & 63;
  const int w    = tid >> 6;           // wave 0..7 -> expert quad within half
  const int tile = blockIdx.x >> 1;    // 256-token tile
  const int eh   = blockIdx.x & 1;     // expert half (32 experts)
  const int kc   = blockIdx.y * kchunk;

  float acc[4][4];
#pragma unroll
  for (int t = 0; t < 4; ++t)
#pragma unroll
    for (int e = 0; e < 4; ++e) acc[t][e] = 0.f;

  const float* xp = x + (size_t)(tile * 256 + lane) * MD + kc;
  // staging: thread covers expert (tid>>4) of the half, k-quad (tid&15)
  const float* wsrc = wg + (size_t)(eh * 32 + (tid >> 4)) * MD + kc + (tid & 15) * 4;
  float* ldst0 = &wlds[0][tid * 4];
  float* ldst1 = &wlds[1][tid * 4];

  const int nsteps = kchunk / 64;

  gload_lds16(wsrc, ldst0);      // prologue stage step 0
  __syncthreads();               // drains vmcnt before barrier

  int buf = 0;
  for (int s = 0; s < nsteps; ++s) {
    if (s + 1 < nsteps)
      gload_lds16(wsrc + (size_t)(s + 1) * 64, buf ? ldst0 : ldst1);
    const float* xs = xp + s * 64;
    const float* wl = &wlds[buf][w * 4 * 64];
#pragma unroll
    for (int kq = 0; kq < 16; ++kq) {
      float4 wv[4];
#pragma unroll
      for (int e = 0; e < 4; ++e)   // wave-uniform address -> LDS broadcast
        wv[e] = *(const float4*)(wl + e * 64 + kq * 4);
      float4 xv[4];
#pragma unroll
      for (int t = 0; t < 4; ++t)
        xv[t] = *(const float4*)(xs + (size_t)t * 64 * MD + kq * 4);
#pragma unroll
      for (int t = 0; t < 4; ++t)
#pragma unroll
        for (int e = 0; e < 4; ++e) {
          acc[t][e] = fmaf(xv[t].x, wv[e].x, acc[t][e]);
          acc[t][e] = fmaf(xv[t].y, wv[e].y, acc[t][e]);
          acc[t][e] = fmaf(xv[t].z, wv[e].z, acc[t][e]);
          acc[t][e] = fmaf(xv[t].w, wv[e].w, acc[t][e]);
        }
    }
    __syncthreads();   // staged tile complete + everyone done reading buf
    buf ^= 1;
  }

  const int c = blockIdx.y;
#pragma unroll
  for (int t = 0; t < 4; ++t) {
    const int tok = tile * 256 + t * 64 + lane;
    float4 v = make_float4(acc[t][0], acc[t][1], acc[t][2], acc[t][3]);
    *(float4*)(part + ((size_t)c * NT + tok) * NE + eh * 32 + w * 4) = v;
  }
}

// K2a: fold k-chunk partials into part[0]. Massively parallel elementwise.
__global__ void k2a_reduce(float* __restrict__ part, int ks) {
  const size_t i = (size_t)blockIdx.x * blockDim.x + threadIdx.x;  // float4 index
  float4* p = (float4*)part;
  float4 v = p[i];
  for (int c = 1; c < ks; ++c) {
    float4 u = p[(size_t)c * (NT * NE / 4) + i];
    v.x += u.x; v.y += u.y; v.z += u.z; v.w += u.w;
  }
  p[i] = v;
}

// K2b: per-token top-2/softmax/gates/idx + per-chunk expert counts, in-chunk
// ranks (ballot/popcount, exact) and gate column sums. grid 128, block 64.
__global__ void k2b_topk(const float* __restrict__ part, float* __restrict__ out,
                         float* __restrict__ me_partial,
                         int* __restrict__ cnt0, int* __restrict__ cnt1,
                         int* __restrict__ rank0, int* __restrict__ rank1) {
  const int lane  = threadIdx.x;
  const int chunk = blockIdx.x;
  const int token = chunk * 64 + lane;

  float l[NE];
  const float4* p4 = (const float4*)(part + (size_t)token * NE);
#pragma unroll
  for (int q = 0; q < 16; ++q) {
    float4 v = p4[q];
    l[4*q+0] = v.x; l[4*q+1] = v.y; l[4*q+2] = v.z; l[4*q+3] = v.w;
  }

  // jax tie-break (lowest index wins): strict > ascending scans
  float m1 = -INFINITY; int i1 = 0;
#pragma unroll
  for (int e = 0; e < NE; ++e) if (l[e] > m1) { m1 = l[e]; i1 = e; }
  float m2 = -INFINITY; int i2 = 0;
#pragma unroll
  for (int e = 0; e < NE; ++e) if (e != i1 && l[e] > m2) { m2 = l[e]; i2 = e; }

  float s = 0.f;
#pragma unroll
  for (int e = 0; e < NE; ++e) { l[e] = __expf(l[e] - m1); s += l[e]; }
  const float inv_s = 1.f / s;

  const float g2 = __expf(m2 - m1);   // normalized top-2: softmax denom cancels
  const float dn = 1.f + g2;
  out[OFF_GATES + token]      = 1.f / dn;
  out[OFF_GATES + NT + token] = g2 / dn;
  out[OFF_IDX + token]        = (float)i1;
  out[OFF_IDX + NT + token]   = (float)i2;

  const unsigned long long below = (1ULL << lane) - 1ULL;
  for (int e = 0; e < NE; ++e) {
    unsigned long long ma = __ballot(i1 == e);
    unsigned long long mb = __ballot(i2 == e);
    if (i1 == e) rank0[token] = __popcll(ma & below);
    if (i2 == e) rank1[token] = __popcll(mb & below);
    if (lane == e) {
      cnt0[chunk * NE + e] = __popcll(ma);
      cnt1[chunk * NE + e] = __popcll(mb);
    }
  }

  // column sums of softmax gates over this chunk (transpose via padded LDS)
  __shared__ float lds[64 * 65];
#pragma unroll
  for (int e = 0; e < NE; ++e) lds[lane * 65 + e] = l[e] * inv_s;
  __syncthreads();
  float col = 0.f;
#pragma unroll
  for (int t = 0; t < 64; ++t) col += lds[t * 65 + lane];
  me_partial[chunk * NE + lane] = col;
}

// K3b: exclusive scan of per-chunk counts (k0 stream then k1 stream, so k1
// bases start at ce[e]), me reduce, l_loss. 1 block, lane = expert.
__global__ void k3b_scan(const int* __restrict__ cnt0, const int* __restrict__ cnt1,
                         int* __restrict__ base0, int* __restrict__ base1,
                         const float* __restrict__ me_partial,
                         float* __restrict__ out) {
  const int e = threadIdx.x;
  int run = 0;
  for (int c = 0; c < NCHUNK; ++c) { base0[c * NE + e] = run; run += cnt0[c * NE + e]; }
  const int ce = run;   // total k0 count for expert e
  for (int c = 0; c < NCHUNK; ++c) { base1[c * NE + e] = run; run += cnt1[c * NE + e]; }
  float me = 0.f;
  for (int c = 0; c < NCHUNK; ++c) me += me_partial[c * NE + e];
  float v = me * (float)ce;
#pragma unroll
  for (int off = 1; off < 64; off <<= 1) v += __shfl_xor(v, off, 64);
  if (e == 0) out[0] = v * ((float)NE / ((float)NT * (float)NT));
}

// K3c: locations = chunk base + in-chunk rank. grid 128, block 64.
__global__ void k3c_loc(float* __restrict__ out,
                        const int* __restrict__ base0, const int* __restrict__ base1,
                        const int* __restrict__ rank0, const int* __restrict__ rank1) {
  const int lane  = threadIdx.x;
  const int chunk = blockIdx.x;
  const int token = chunk * 64 + lane;
  const int i1 = (int)out[OFF_IDX + token];
  const int i2 = (int)out[OFF_IDX + NT + token];
  out[OFF_LOC + token]      = (float)(base0[chunk * NE + i1] + rank0[token]);
  out[OFF_LOC + NT + token] = (float)(base1[chunk * NE + i2] + rank1[token]);
}

extern "C" void kernel_launch(void* const* d_in, const int* in_sizes, int n_in,
                              void* d_out, int out_size, void* d_ws, size_t ws_size,
                              hipStream_t stream) {
  const float* x  = (const float*)d_in[0];
  const float* wg = (const float*)d_in[1];
  float* out = (float*)d_out;

  // k-split: 8 preferred (4096 waves in k1); degrade if workspace is small
  int ks = 8;
  while (ks > 1 &&
         ((size_t)ks * NT * NE + 7 * (size_t)NCHUNK * NE) * sizeof(float) > ws_size)
    ks >>= 1;
  const int kchunk = MD / ks;

  float* part       = (float*)d_ws;                       // [ks][NT][NE]
  float* me_partial = part + (size_t)ks * NT * NE;        // [128][64]
  int*   cnt0  = (int*)(me_partial + NCHUNK * NE);        // [128][64]
  int*   cnt1  = cnt0  + NCHUNK * NE;
  int*   base0 = cnt1  + NCHUNK * NE;
  int*   base1 = base0 + NCHUNK * NE;
  int*   rank0 = base1 + NCHUNK * NE;                     // [NT]
  int*   rank1 = rank0 + NT;

  hipLaunchKernelGGL(k1_gemm, dim3(64, ks), dim3(512), 0, stream, x, wg, part, kchunk);
  if (ks > 1)
    hipLaunchKernelGGL(k2a_reduce, dim3(NT * NE / 4 / 256), dim3(256), 0, stream, part, ks);
  hipLaunchKernelGGL(k2b_topk, dim3(NCHUNK), dim3(64), 0, stream,
                     part, out, me_partial, cnt0, cnt1, rank0, rank1);
  hipLaunchKernelGGL(k3b_scan, dim3(1), dim3(64), 0, stream,
                     cnt0, cnt1, base0, base1, me_partial, out);
  hipLaunchKernelGGL(k3c_loc, dim3(NCHUNK), dim3(64), 0, stream,
                     out, base0, base1, rank0, rank1);
}

// Round 3
// 103.177 us; speedup vs baseline: 3.6277x; 2.8291x over previous
//
#include <hip/hip_runtime.h>
#include <cmath>
#include <cstdint>
#include <cstddef>

#define NT 8192   // tokens
#define MD 4096   // model dim
#define NE 64     // experts
#define NCHUNK 128  // NT/64

// Output layout (all float32):
// [0] l_loss | gates_k[2][NT] | idx[2][NT] | locations[2][NT]
static constexpr int OFF_GATES = 1;
static constexpr int OFF_IDX   = 1 + 2 * NT;
static constexpr int OFF_LOC   = 1 + 4 * NT;

__device__ __forceinline__ void gload_lds16(const float* g, float* l) {
  __builtin_amdgcn_global_load_lds(
      (const __attribute__((address_space(1))) void*)g,
      (__attribute__((address_space(3))) void*)l, 16, 0, 0);
}

// K1: logits-partial = x[128-token tile] . wg^T (all 64 experts) over a
// 512-wide k-chunk. 256 threads (4 waves); thread tile = 4 tokens x 8 experts.
// x staged in LDS with XOR swizzle (source-side, linear LDS dest); w staged
// linear, read as 2-address broadcast. Double-buffered 2-phase pipeline.
// Summation order per (token,expert): strictly ascending k within the chunk —
// bitwise identical to the round-2 kernel that passed.
#define TTILE 128
#define KSTEP 32
__global__ __launch_bounds__(256, 2)
void k1_gemm(const float* __restrict__ x, const float* __restrict__ wg,
             float* __restrict__ part, int kchunk) {
  __shared__ float xls[2][TTILE * KSTEP];  // 16 KB each; slot(row, c4): data col4 = c4 ^ (row&7)
  __shared__ float wls[2][NE * KSTEP];     // 8 KB each; linear [e][k]
  const int tid   = threadIdx.x;
  const int tslot = tid & 31;
  const int eslot = tid >> 5;              // 0..7 -> experts eslot*8..+7
  const int tile  = blockIdx.x;
  const int kc    = blockIdx.y * kchunk;

  float acc[4][8];
#pragma unroll
  for (int t = 0; t < 4; ++t)
#pragma unroll
    for (int e = 0; e < 8; ++e) acc[t][e] = 0.f;

  auto stage = [&](int sbuf, int k0) {
#pragma unroll
    for (int j = 0; j < 4; ++j) {          // x: 1024 16B slots / 256 thr
      const int L16 = tid + j * 256;
      const int row = L16 >> 3;
      const int c4  = (L16 & 7) ^ (row & 7);   // inverse swizzle on source
      gload_lds16(x + (size_t)(tile * TTILE + row) * MD + k0 + c4 * 4,
                  &xls[sbuf][L16 * 4]);
    }
#pragma unroll
    for (int j = 0; j < 2; ++j) {          // w: 512 slots / 256 thr
      const int L16 = tid + j * 256;
      gload_lds16(wg + (size_t)(L16 >> 3) * MD + k0 + (L16 & 7) * 4,
                  &wls[sbuf][L16 * 4]);
    }
  };

  stage(0, kc);
  __syncthreads();

  const int nsteps = kchunk / KSTEP;
  int buf = 0;
  for (int s = 0; s < nsteps; ++s) {
    if (s + 1 < nsteps) stage(buf ^ 1, kc + (s + 1) * KSTEP);
    const float* xb = xls[buf];
    const float* wb = wls[buf];
    const int scc = tslot & 7;             // row&7 is tslot&7 for all tt
#pragma unroll
    for (int kq = 0; kq < 8; ++kq) {
      float4 wv[8];
#pragma unroll
      for (int ee = 0; ee < 8; ++ee)       // 2-address broadcast (eslot pair)
        wv[ee] = *(const float4*)(wb + (eslot * 8 + ee) * KSTEP + kq * 4);
      float4 xv[4];
#pragma unroll
      for (int tt = 0; tt < 4; ++tt) {
        const int row = tt * 32 + tslot;
        xv[tt] = *(const float4*)(xb + row * KSTEP + ((kq ^ scc) << 2));
      }
#pragma unroll
      for (int tt = 0; tt < 4; ++tt)
#pragma unroll
        for (int ee = 0; ee < 8; ++ee) {
          acc[tt][ee] = fmaf(xv[tt].x, wv[ee].x, acc[tt][ee]);
          acc[tt][ee] = fmaf(xv[tt].y, wv[ee].y, acc[tt][ee]);
          acc[tt][ee] = fmaf(xv[tt].z, wv[ee].z, acc[tt][ee]);
          acc[tt][ee] = fmaf(xv[tt].w, wv[ee].w, acc[tt][ee]);
        }
    }
    __syncthreads();
    buf ^= 1;
  }

  const int c = blockIdx.y;
#pragma unroll
  for (int tt = 0; tt < 4; ++tt) {
    const int tok = tile * TTILE + tt * 32 + tslot;
    float* pp = part + ((size_t)c * NT + tok) * NE + eslot * 8;
    *(float4*)(pp)     = make_float4(acc[tt][0], acc[tt][1], acc[tt][2], acc[tt][3]);
    *(float4*)(pp + 4) = make_float4(acc[tt][4], acc[tt][5], acc[tt][6], acc[tt][7]);
  }
}

// K2a: fold k-chunk partials into part[0], chunk-ascending (same order as the
// round-2 fold). Coalesced float4 streams.
__global__ void k2a_reduce(float* __restrict__ part, int ks) {
  const size_t i = (size_t)blockIdx.x * blockDim.x + threadIdx.x;
  float4* p = (float4*)part;
  float4 v = p[i];
  for (int c = 1; c < ks; ++c) {
    float4 u = p[(size_t)c * (NT * NE / 4) + i];
    v.x += u.x; v.y += u.y; v.z += u.z; v.w += u.w;
  }
  p[i] = v;
}

// K2b: per-token top-2/softmax/gates/idx + per-chunk counts, in-chunk ranks
// (ballot/popcount, exact), gate column sums. grid 128, block 64.
__global__ void k2b_topk(const float* __restrict__ part, float* __restrict__ out,
                         float* __restrict__ me_partial,
                         int* __restrict__ cnt0, int* __restrict__ cnt1,
                         int* __restrict__ rank0, int* __restrict__ rank1) {
  const int lane  = threadIdx.x;
  const int chunk = blockIdx.x;
  const int token = chunk * 64 + lane;

  float l[NE];
  const float4* p4 = (const float4*)(part + (size_t)token * NE);
#pragma unroll
  for (int q = 0; q < 16; ++q) {
    float4 v = p4[q];
    l[4*q+0] = v.x; l[4*q+1] = v.y; l[4*q+2] = v.z; l[4*q+3] = v.w;
  }

  // jax tie-break (lowest index wins): strict > ascending scans
  float m1 = -INFINITY; int i1 = 0;
#pragma unroll
  for (int e = 0; e < NE; ++e) if (l[e] > m1) { m1 = l[e]; i1 = e; }
  float m2 = -INFINITY; int i2 = 0;
#pragma unroll
  for (int e = 0; e < NE; ++e) if (e != i1 && l[e] > m2) { m2 = l[e]; i2 = e; }

  float s = 0.f;
#pragma unroll
  for (int e = 0; e < NE; ++e) { l[e] = __expf(l[e] - m1); s += l[e]; }
  const float inv_s = 1.f / s;

  const float g2 = __expf(m2 - m1);   // normalized top-2: softmax denom cancels
  const float dn = 1.f + g2;
  out[OFF_GATES + token]      = 1.f / dn;
  out[OFF_GATES + NT + token] = g2 / dn;
  out[OFF_IDX + token]        = (float)i1;
  out[OFF_IDX + NT + token]   = (float)i2;

  const unsigned long long below = (1ULL << lane) - 1ULL;
  for (int e = 0; e < NE; ++e) {
    unsigned long long ma = __ballot(i1 == e);
    unsigned long long mb = __ballot(i2 == e);
    if (i1 == e) rank0[token] = __popcll(ma & below);
    if (i2 == e) rank1[token] = __popcll(mb & below);
    if (lane == e) {
      cnt0[chunk * NE + e] = __popcll(ma);
      cnt1[chunk * NE + e] = __popcll(mb);
    }
  }

  // column sums of softmax gates over this chunk (transpose via padded LDS)
  __shared__ float lds[64 * 65];
#pragma unroll
  for (int e = 0; e < NE; ++e) lds[lane * 65 + e] = l[e] * inv_s;
  __syncthreads();
  float col = 0.f;
#pragma unroll
  for (int t = 0; t < 64; ++t) col += lds[t * 65 + lane];
  me_partial[chunk * NE + lane] = col;
}

// K3b: exclusive scan of per-chunk counts (k0 then k1 so k1 bases start at
// ce[e]), me reduce, l_loss. 1 block, lane = expert.
__global__ void k3b_scan(const int* __restrict__ cnt0, const int* __restrict__ cnt1,
                         int* __restrict__ base0, int* __restrict__ base1,
                         const float* __restrict__ me_partial,
                         float* __restrict__ out) {
  const int e = threadIdx.x;
  int run = 0;
  for (int c = 0; c < NCHUNK; ++c) { base0[c * NE + e] = run; run += cnt0[c * NE + e]; }
  const int ce = run;
  for (int c = 0; c < NCHUNK; ++c) { base1[c * NE + e] = run; run += cnt1[c * NE + e]; }
  float me = 0.f;
  for (int c = 0; c < NCHUNK; ++c) me += me_partial[c * NE + e];
  float v = me * (float)ce;
#pragma unroll
  for (int off = 1; off < 64; off <<= 1) v += __shfl_xor(v, off, 64);
  if (e == 0) out[0] = v * ((float)NE / ((float)NT * (float)NT));
}

// K3c: locations = chunk base + in-chunk rank. grid 128, block 64.
__global__ void k3c_loc(float* __restrict__ out,
                        const int* __restrict__ base0, const int* __restrict__ base1,
                        const int* __restrict__ rank0, const int* __restrict__ rank1) {
  const int lane  = threadIdx.x;
  const int chunk = blockIdx.x;
  const int token = chunk * 64 + lane;
  const int i1 = (int)out[OFF_IDX + token];
  const int i2 = (int)out[OFF_IDX + NT + token];
  out[OFF_LOC + token]      = (float)(base0[chunk * NE + i1] + rank0[token]);
  out[OFF_LOC + NT + token] = (float)(base1[chunk * NE + i2] + rank1[token]);
}

extern "C" void kernel_launch(void* const* d_in, const int* in_sizes, int n_in,
                              void* d_out, int out_size, void* d_ws, size_t ws_size,
                              hipStream_t stream) {
  const float* x  = (const float*)d_in[0];
  const float* wg = (const float*)d_in[1];
  float* out = (float*)d_out;

  int ks = 8;
  while (ks > 1 &&
         ((size_t)ks * NT * NE + 7 * (size_t)NCHUNK * NE) * sizeof(float) > ws_size)
    ks >>= 1;
  const int kchunk = MD / ks;

  float* part       = (float*)d_ws;                       // [ks][NT][NE]
  float* me_partial = part + (size_t)ks * NT * NE;        // [128][64]
  int*   cnt0  = (int*)(me_partial + NCHUNK * NE);
  int*   cnt1  = cnt0  + NCHUNK * NE;
  int*   base0 = cnt1  + NCHUNK * NE;
  int*   base1 = base0 + NCHUNK * NE;
  int*   rank0 = base1 + NCHUNK * NE;                     // [NT]
  int*   rank1 = rank0 + NT;

  hipLaunchKernelGGL(k1_gemm, dim3(NT / TTILE, ks), dim3(256), 0, stream,
                     x, wg, part, kchunk);
  if (ks > 1)
    hipLaunchKernelGGL(k2a_reduce, dim3(NT * NE / 4 / 256), dim3(256), 0, stream, part, ks);
  hipLaunchKernelGGL(k2b_topk, dim3(NCHUNK), dim3(64), 0, stream,
                     part, out, me_partial, cnt0, cnt1, rank0, rank1);
  hipLaunchKernelGGL(k3b_scan, dim3(1), dim3(64), 0, stream,
                     cnt0, cnt1, base0, base1, me_partial, out);
  hipLaunchKernelGGL(k3c_loc, dim3(NCHUNK), dim3(64), 0, stream,
                     out, base0, base1, rank0, rank1);
}

// Round 4
// 66.198 us; speedup vs baseline: 5.6541x; 1.5586x over previous
//
#include <hip/hip_runtime.h>
#include <cmath>
#include <cstdint>
#include <cstddef>

#define NT 8192     // tokens
#define MD 4096     // model dim
#define NE 64       // experts
#define NCHUNK 128  // NT/64

// Output layout (all float32):
// [0] l_loss | gates_k[2][NT] | idx[2][NT] | locations[2][NT]
static constexpr int OFF_GATES = 1;
static constexpr int OFF_IDX   = 1 + 2 * NT;
static constexpr int OFF_LOC   = 1 + 4 * NT;

typedef __attribute__((ext_vector_type(8))) short short8_t;  // 8 bf16 (4 VGPR)
typedef __attribute__((ext_vector_type(4))) float f32x4;     // MFMA C/D

#define BM    64   // tokens per block
#define KSTEP 32   // k per pipeline step (= MFMA K depth)
#define ROWP  40   // padded row stride in shorts (32 bf16 + 8 pad = 80 B):
                   // 20-dword stride, gcd(20,32)=4 -> rows walk all 8 bank
                   // groups with period 8 -> uniform 8 dwords/bank (floor)

// Exact 3-way truncation split: x == h + m + s + r, |r| <= 2^-24 |x|.
// h,m,s are bf16 bit patterns; subtractions are exact (Dekker-style).
__device__ __forceinline__ void split3(float v, short& h, short& m, short& s) {
  unsigned bx = __float_as_uint(v);
  h = (short)(bx >> 16);
  float r1 = v - __uint_as_float(bx & 0xFFFF0000u);
  unsigned b1 = __float_as_uint(r1);
  m = (short)(b1 >> 16);
  float r2 = r1 - __uint_as_float(b1 & 0xFFFF0000u);
  s = (short)(__float_as_uint(r2) >> 16);
}

// K1: logits-partial = x[64-token tile] . wg^T (all 64 experts) over a
// k-chunk, via bf16 MFMA with 3-way split (6 term-pairs == fp32 accuracy).
// 256 thr = 4 waves; wave = 16 tokens x 64 experts (1x4 frags of 16x16x32).
// Double-buffered LDS, reg-staged global->cvt->ds_write, 1 barrier/step.
__global__ __launch_bounds__(256, 2)
void k1_gemm(const float* __restrict__ x, const float* __restrict__ wg,
             float* __restrict__ part, int kchunk) {
  __shared__ short Ah[2][BM * ROWP], Am[2][BM * ROWP], As[2][BM * ROWP];
  __shared__ short Bh[2][NE * ROWP], Bm[2][NE * ROWP], Bs[2][NE * ROWP];
  const int tid  = threadIdx.x;
  const int lane = tid & 63;
  const int w    = tid >> 6;         // wave 0..3 -> token group
  const int mt   = blockIdx.x;
  const int kc   = blockIdx.y * kchunk;
  const int NS   = kchunk / KSTEP;

  const int srow = tid >> 2;         // staging row 0..63 (token / expert)
  const int soct = tid & 3;          // k-octet 0..3 (lanes 0..3 -> 128B coalesced)
  const float* xsrc = x  + (size_t)(mt * BM + srow) * MD + kc + soct * 8;
  const float* wsrc = wg + (size_t)srow * MD + kc + soct * 8;

  f32x4 acc[4];
#pragma unroll
  for (int n = 0; n < 4; ++n) acc[n] = (f32x4){0.f, 0.f, 0.f, 0.f};

  float4 rx0, rx1, rw0, rw1;         // in-flight staging registers
  auto load_regs = [&](int s) {
    const float4* p = (const float4*)(xsrc + (size_t)s * KSTEP);
    rx0 = p[0]; rx1 = p[1];
    const float4* q = (const float4*)(wsrc + (size_t)s * KSTEP);
    rw0 = q[0]; rw1 = q[1];
  };

  const int soff = srow * ROWP + soct * 8;   // byte = srow*80 + soct*16 (16B aligned)
  auto cvt_write = [&](int buf) {
    float vx[8] = {rx0.x, rx0.y, rx0.z, rx0.w, rx1.x, rx1.y, rx1.z, rx1.w};
    float vw[8] = {rw0.x, rw0.y, rw0.z, rw0.w, rw1.x, rw1.y, rw1.z, rw1.w};
    short8_t h, m, s;
#pragma unroll
    for (int i = 0; i < 8; ++i) { short a, b, c; split3(vx[i], a, b, c); h[i] = a; m[i] = b; s[i] = c; }
    *(short8_t*)&Ah[buf][soff] = h;
    *(short8_t*)&Am[buf][soff] = m;
    *(short8_t*)&As[buf][soff] = s;
#pragma unroll
    for (int i = 0; i < 8; ++i) { short a, b, c; split3(vw[i], a, b, c); h[i] = a; m[i] = b; s[i] = c; }
    *(short8_t*)&Bh[buf][soff] = h;
    *(short8_t*)&Bm[buf][soff] = m;
    *(short8_t*)&Bs[buf][soff] = s;
  };

  // Fragment addressing (m89-verified family): A row = lane&15 (within wave's
  // 16 tokens), k = 8*(lane>>4)+i; B col(expert-row) = lane&15, same k.
  const int aoff = (w * 16 + (lane & 15)) * ROWP + (lane >> 4) * 8;
  const int boff0 = (lane & 15) * ROWP + (lane >> 4) * 8;

  auto compute = [&](int buf) {
    short8_t a_h = *(const short8_t*)&Ah[buf][aoff];
    short8_t a_m = *(const short8_t*)&Am[buf][aoff];
    short8_t a_s = *(const short8_t*)&As[buf][aoff];
#pragma unroll
    for (int n = 0; n < 4; ++n) {
      const int bo = boff0 + n * 16 * ROWP;
      short8_t b_h = *(const short8_t*)&Bh[buf][bo];
      short8_t b_m = *(const short8_t*)&Bm[buf][bo];
      short8_t b_s = *(const short8_t*)&Bs[buf][bo];
      acc[n] = __builtin_amdgcn_mfma_f32_16x16x32_bf16(a_h, b_h, acc[n], 0, 0, 0);
      acc[n] = __builtin_amdgcn_mfma_f32_16x16x32_bf16(a_h, b_m, acc[n], 0, 0, 0);
      acc[n] = __builtin_amdgcn_mfma_f32_16x16x32_bf16(a_m, b_h, acc[n], 0, 0, 0);
      acc[n] = __builtin_amdgcn_mfma_f32_16x16x32_bf16(a_h, b_s, acc[n], 0, 0, 0);
      acc[n] = __builtin_amdgcn_mfma_f32_16x16x32_bf16(a_s, b_h, acc[n], 0, 0, 0);
      acc[n] = __builtin_amdgcn_mfma_f32_16x16x32_bf16(a_m, b_m, acc[n], 0, 0, 0);
    }
  };

  load_regs(0);
  cvt_write(0);                 // compiler inserts vmcnt wait at first reg use
  __syncthreads();

  int buf = 0;
  for (int s = 0; s < NS; ++s) {
    if (s + 1 < NS) load_regs(s + 1);   // issue early: HBM hides under compute
    compute(buf);                        // reads buf
    if (s + 1 < NS) cvt_write(buf ^ 1);  // writes other buffer (no conflict)
    __syncthreads();                     // single barrier per step
    buf ^= 1;
  }

  // D layout: col = lane&15 (expert), row = 4*(lane>>4) + r (token)
  const int c   = blockIdx.y;
  const int col = lane & 15;
  const int rq  = lane >> 4;
#pragma unroll
  for (int n = 0; n < 4; ++n)
#pragma unroll
    for (int r = 0; r < 4; ++r) {
      const int tok = mt * BM + w * 16 + rq * 4 + r;
      part[((size_t)c * NT + tok) * NE + n * 16 + col] = acc[n][r];
    }
}

// K2a: fold k-chunk partials into part[0], chunk-ascending. Coalesced float4.
__global__ void k2a_reduce(float* __restrict__ part, int ks) {
  const size_t i = (size_t)blockIdx.x * blockDim.x + threadIdx.x;
  float4* p = (float4*)part;
  float4 v = p[i];
  for (int c = 1; c < ks; ++c) {
    float4 u = p[(size_t)c * (NT * NE / 4) + i];
    v.x += u.x; v.y += u.y; v.z += u.z; v.w += u.w;
  }
  p[i] = v;
}

// K2b: per-token top-2/softmax/gates/idx + per-chunk counts, in-chunk ranks
// (ballot/popcount, exact), gate column sums. grid 128, block 64.
__global__ void k2b_topk(const float* __restrict__ part, float* __restrict__ out,
                         float* __restrict__ me_partial,
                         int* __restrict__ cnt0, int* __restrict__ cnt1,
                         int* __restrict__ rank0, int* __restrict__ rank1) {
  const int lane  = threadIdx.x;
  const int chunk = blockIdx.x;
  const int token = chunk * 64 + lane;

  float l[NE];
  const float4* p4 = (const float4*)(part + (size_t)token * NE);
#pragma unroll
  for (int q = 0; q < 16; ++q) {
    float4 v = p4[q];
    l[4*q+0] = v.x; l[4*q+1] = v.y; l[4*q+2] = v.z; l[4*q+3] = v.w;
  }

  // jax tie-break (lowest index wins): strict > ascending scans
  float m1 = -INFINITY; int i1 = 0;
#pragma unroll
  for (int e = 0; e < NE; ++e) if (l[e] > m1) { m1 = l[e]; i1 = e; }
  float m2 = -INFINITY; int i2 = 0;
#pragma unroll
  for (int e = 0; e < NE; ++e) if (e != i1 && l[e] > m2) { m2 = l[e]; i2 = e; }

  float s = 0.f;
#pragma unroll
  for (int e = 0; e < NE; ++e) { l[e] = __expf(l[e] - m1); s += l[e]; }
  const float inv_s = 1.f / s;

  const float g2 = __expf(m2 - m1);   // normalized top-2: softmax denom cancels
  const float dn = 1.f + g2;
  out[OFF_GATES + token]      = 1.f / dn;
  out[OFF_GATES + NT + token] = g2 / dn;
  out[OFF_IDX + token]        = (float)i1;
  out[OFF_IDX + NT + token]   = (float)i2;

  const unsigned long long below = (1ULL << lane) - 1ULL;
  for (int e = 0; e < NE; ++e) {
    unsigned long long ma = __ballot(i1 == e);
    unsigned long long mb = __ballot(i2 == e);
    if (i1 == e) rank0[token] = __popcll(ma & below);
    if (i2 == e) rank1[token] = __popcll(mb & below);
    if (lane == e) {
      cnt0[chunk * NE + e] = __popcll(ma);
      cnt1[chunk * NE + e] = __popcll(mb);
    }
  }

  // column sums of softmax gates over this chunk (transpose via padded LDS)
  __shared__ float lds[64 * 65];
#pragma unroll
  for (int e = 0; e < NE; ++e) lds[lane * 65 + e] = l[e] * inv_s;
  __syncthreads();
  float col = 0.f;
#pragma unroll
  for (int t = 0; t < 64; ++t) col += lds[t * 65 + lane];
  me_partial[chunk * NE + lane] = col;
}

// K3b: exclusive scan of per-chunk counts (k0 then k1 so k1 bases start at
// ce[e]), me reduce, l_loss. 1 block, lane = expert.
__global__ void k3b_scan(const int* __restrict__ cnt0, const int* __restrict__ cnt1,
                         int* __restrict__ base0, int* __restrict__ base1,
                         const float* __restrict__ me_partial,
                         float* __restrict__ out) {
  const int e = threadIdx.x;
  int run = 0;
  for (int c = 0; c < NCHUNK; ++c) { base0[c * NE + e] = run; run += cnt0[c * NE + e]; }
  const int ce = run;
  for (int c = 0; c < NCHUNK; ++c) { base1[c * NE + e] = run; run += cnt1[c * NE + e]; }
  float me = 0.f;
  for (int c = 0; c < NCHUNK; ++c) me += me_partial[c * NE + e];
  float v = me * (float)ce;
#pragma unroll
  for (int off = 1; off < 64; off <<= 1) v += __shfl_xor(v, off, 64);
  if (e == 0) out[0] = v * ((float)NE / ((float)NT * (float)NT));
}

// K3c: locations = chunk base + in-chunk rank. grid 128, block 64.
__global__ void k3c_loc(float* __restrict__ out,
                        const int* __restrict__ base0, const int* __restrict__ base1,
                        const int* __restrict__ rank0, const int* __restrict__ rank1) {
  const int lane  = threadIdx.x;
  const int chunk = blockIdx.x;
  const int token = chunk * 64 + lane;
  const int i1 = (int)out[OFF_IDX + token];
  const int i2 = (int)out[OFF_IDX + NT + token];
  out[OFF_LOC + token]      = (float)(base0[chunk * NE + i1] + rank0[token]);
  out[OFF_LOC + NT + token] = (float)(base1[chunk * NE + i2] + rank1[token]);
}

extern "C" void kernel_launch(void* const* d_in, const int* in_sizes, int n_in,
                              void* d_out, int out_size, void* d_ws, size_t ws_size,
                              hipStream_t stream) {
  const float* x  = (const float*)d_in[0];
  const float* wg = (const float*)d_in[1];
  float* out = (float*)d_out;

  int ks = 4;   // 512 blocks = 2/CU
  while (ks > 1 &&
         ((size_t)ks * NT * NE + 7 * (size_t)NCHUNK * NE) * sizeof(float) > ws_size)
    ks >>= 1;
  const int kchunk = MD / ks;

  float* part       = (float*)d_ws;                       // [ks][NT][NE]
  float* me_partial = part + (size_t)ks * NT * NE;        // [128][64]
  int*   cnt0  = (int*)(me_partial + NCHUNK * NE);
  int*   cnt1  = cnt0  + NCHUNK * NE;
  int*   base0 = cnt1  + NCHUNK * NE;
  int*   base1 = base0 + NCHUNK * NE;
  int*   rank0 = base1 + NCHUNK * NE;                     // [NT]
  int*   rank1 = rank0 + NT;

  hipLaunchKernelGGL(k1_gemm, dim3(NT / BM, ks), dim3(256), 0, stream,
                     x, wg, part, kchunk);
  if (ks > 1)
    hipLaunchKernelGGL(k2a_reduce, dim3(NT * NE / 4 / 256), dim3(256), 0, stream, part, ks);
  hipLaunchKernelGGL(k2b_topk, dim3(NCHUNK), dim3(64), 0, stream,
                     part, out, me_partial, cnt0, cnt1, rank0, rank1);
  hipLaunchKernelGGL(k3b_scan, dim3(1), dim3(64), 0, stream,
                     cnt0, cnt1, base0, base1, me_partial, out);
  hipLaunchKernelGGL(k3c_loc, dim3(NCHUNK), dim3(64), 0, stream,
                     out, base0, base1, rank0, rank1);
}